// Round 4
// baseline (140.459 us; speedup 1.0000x reference)
//
#include <hip/hip_runtime.h>
#include <hip/hip_bf16.h>
#include <cstdint>

#define D_MODEL 512
#define NHEADS 8
#define HDIM 64
#define SEQ 4096
#define BATCH 2
#define NTOK (BATCH*SEQ)

typedef __bf16 bf16;
typedef __bf16 bfv8 __attribute__((ext_vector_type(8)));
typedef __bf16 bfv4 __attribute__((ext_vector_type(4)));
typedef float f32x4 __attribute__((ext_vector_type(4)));
typedef unsigned u32x2 __attribute__((ext_vector_type(2)));

__device__ __forceinline__ void gload_lds16(const void* g, void* l) {
  __builtin_amdgcn_global_load_lds(
      (const __attribute__((address_space(1))) void*)(uintptr_t)g,
      (__attribute__((address_space(3))) void*)(uintptr_t)l,
      16, 0, 0);
}
__device__ __forceinline__ float exp2_hw(float x) {
  float r; asm("v_exp_f32 %0, %1" : "=v"(r) : "v"(x)); return r;
}
__device__ __forceinline__ unsigned cvtpk_bf16(float lo, float hi) {
  unsigned r; asm("v_cvt_pk_bf16_f32 %0, %1, %2" : "=v"(r) : "v"(lo), "v"(hi)); return r;
}
__device__ __forceinline__ float bpermf(int addr, float v) {
  return __int_as_float(__builtin_amdgcn_ds_bpermute(addr, __float_as_int(v)));
}
__device__ __forceinline__ void swap32(float x, float& a, float& b) {
  u32x2 r = __builtin_amdgcn_permlane32_swap(__float_as_uint(x), __float_as_uint(x), false, false);
  a = __uint_as_float(r[0]); b = __uint_as_float(r[1]);
}

// ---------------- converters ----------------
__global__ void k_cvt(const float* __restrict__ in, bf16* __restrict__ out, int n) {
  int i = (blockIdx.x * blockDim.x + threadIdx.x) * 4;
  if (i < n) {
    const float4 v = *(const float4*)(in + i);
    bfv4 b;
    b[0] = (bf16)v.x; b[1] = (bf16)v.y; b[2] = (bf16)v.z; b[3] = (bf16)v.w;
    *(bfv4*)(out + i) = b;
  }
}

__global__ __launch_bounds__(256) void k_cvt_t(
    const float* __restrict__ w, bf16* __restrict__ wt, int K, int N) {
  __shared__ float tile[64][65];
  const int n0 = blockIdx.x * 64, k0 = blockIdx.y * 64;
  const int c = threadIdx.x & 63, r0 = threadIdx.x >> 6;
#pragma unroll
  for (int i = 0; i < 16; ++i) {
    const int r = r0 + i * 4;
    tile[r][c] = w[(size_t)(k0 + r) * N + n0 + c];
  }
  __syncthreads();
#pragma unroll
  for (int i = 0; i < 16; ++i) {
    const int r = r0 + i * 4;
    wt[(size_t)(n0 + r) * K + k0 + c] = (bf16)tile[c][r];
  }
}

// ---------------- GEMM C = A * Bt^T (+bias), BK=64, source-swizzled staging ----
template<int EPI>
__global__ __launch_bounds__(256) void k_gemm_bt(
    const bf16* __restrict__ A, const bf16* __restrict__ Bt,
    const float* __restrict__ bias,
    float* __restrict__ Cf,
    bf16* __restrict__ Qo, bf16* __restrict__ Ko, bf16* __restrict__ Vo)
{
  __shared__ __align__(16) bf16 As[128 * 64];
  __shared__ __align__(16) bf16 Bs[128 * 64];
  const int t = threadIdx.x;
  const int lane = t & 63;
  const int w = t >> 6;
  const int wm = w >> 1, wn = w & 1;
  const int l15 = lane & 15, l4 = lane >> 4;
  const int bm = blockIdx.y, bn = blockIdx.x;

  // 1024 16B-chunks per tensor; thread t stages chunks t+i*256.
  // chunk ch -> LDS row=ch>>3, slot=ch&7; global col = (slot ^ (row&7))*8.
  const bf16* gAc[4]; const bf16* gBc[4];
#pragma unroll
  for (int i = 0; i < 4; ++i) {
    const int ch = t + i * 256;
    const int r = ch >> 3, c = ((ch & 7) ^ (r & 7)) * 8;
    gAc[i] = A + (size_t)(bm * 128 + r) * D_MODEL + c;
    gBc[i] = Bt + (size_t)(bn * 128 + r) * D_MODEL + c;
  }

  f32x4 acc[4][4] = {};

  for (int kt = 0; kt < D_MODEL / 64; ++kt) {
    const int k0 = kt * 64;
#pragma unroll
    for (int i = 0; i < 4; ++i) {
      gload_lds16(gAc[i] + k0, &As[(t + i * 256) * 8]);
      gload_lds16(gBc[i] + k0, &Bs[(t + i * 256) * 8]);
    }
    __syncthreads();
#pragma unroll
    for (int kk = 0; kk < 2; ++kk) {
      const int co = ((kk * 4 + l4) ^ (l15 & 7)) * 8;
      bfv8 af[4], bfr[4];
#pragma unroll
      for (int m = 0; m < 4; ++m)
        af[m] = *(const bfv8*)&As[(wm * 64 + m * 16 + l15) * 64 + co];
#pragma unroll
      for (int n = 0; n < 4; ++n)
        bfr[n] = *(const bfv8*)&Bs[(wn * 64 + n * 16 + l15) * 64 + co];
#pragma unroll
      for (int m = 0; m < 4; ++m)
#pragma unroll
        for (int n = 0; n < 4; ++n)
          acc[m][n] = __builtin_amdgcn_mfma_f32_16x16x32_bf16(af[m], bfr[n], acc[m][n], 0, 0, 0);
    }
    __syncthreads();
  }

#pragma unroll
  for (int m = 0; m < 4; ++m) {
#pragma unroll
    for (int n = 0; n < 4; ++n) {
      const int col = bn * 128 + wn * 64 + n * 16 + l15;
      const float bv = bias[col];
#pragma unroll
      for (int r = 0; r < 4; ++r) {
        const int row = bm * 128 + wm * 64 + m * 16 + l4 * 4 + r;
        const float val = acc[m][n][r] + bv;
        if constexpr (EPI == 0) {
          Cf[(size_t)row * D_MODEL + col] = val;
        } else {
          const int which = col >> 9;
          const int rem = col & 511;
          const int h = rem >> 6, dd = rem & 63;
          const int b = row >> 12, s = row & 4095;
          const int bh = b * NHEADS + h;
          if (which == 0)
            Qo[(((size_t)bh) * SEQ + s) * HDIM + dd] = (bf16)(val * 0.18033688f); // 1/8*log2(e)
          else if (which == 1)
            Ko[(((size_t)bh) * SEQ + s) * HDIM + dd] = (bf16)val;
          else
            Vo[(((size_t)bh) * HDIM + dd) * SEQ + s] = (bf16)val;  // transposed
        }
      }
    }
  }
}

// ---------------- causal flash attention ----------------
// 512 blocks, zigzag qt for CU load balance; 8 waves x 16 q-rows (QBLK=128).
// Swapped QK^T pipelined one tile ahead; K/V triple-buffered (prefetch dist 2).
__global__ __launch_bounds__(512, 4) void k_attn(
    const bf16* __restrict__ Q, const bf16* __restrict__ Kg,
    const bf16* __restrict__ Vt, bf16* __restrict__ O)
{
  __shared__ __align__(16) bf16 Kl[3][4096];
  __shared__ __align__(16) bf16 Vl[3][4096];
  __shared__ __align__(16) bf16 Pl[8][1152];   // per-wave [16 q][72]
  const int t = threadIdx.x;
  const int lane = t & 63, w = t >> 6;
  const int l15 = lane & 15, l4 = lane >> 4;
  const int bx = blockIdx.x;
  const int bh = bx & 15;
  const int qt = (bx < 256) ? (31 - (bx >> 4)) : ((bx - 256) >> 4);  // zigzag pairs
  const size_t kqbase = (size_t)bh * SEQ * HDIM;
  const size_t vbase  = (size_t)bh * HDIM * SEQ;
  const int q0 = qt * 128;

  const int r0 = t >> 3, c0 = ((t & 7) ^ (r0 & 7)) * 8;
  const bf16* kgp = Kg + kqbase + (size_t)r0 * HDIM + c0;
  const bf16* vgp = Vt + vbase + (size_t)r0 * SEQ + c0;

  bfv8 qf[2];
  {
    const bf16* qp = Q + kqbase + (size_t)(q0 + w * 16 + l15) * HDIM + l4 * 8;
    qf[0] = *(const bfv8*)qp;
    qf[1] = *(const bfv8*)(qp + 32);
  }
  const int qg = q0 + w * 16 + l15;
  const int wqmax = q0 + w * 16 + 15;
  const int bp[4] = { l4 * 16, l4 * 16 + 4, l4 * 16 + 8, l4 * 16 + 12 };

  f32x4 oacc[4] = {};
  float mreg = -1e30f;
  float lreg = 0.f;

  const int nt = 2 * qt + 2;   // >= 2

  // prologue: stage tiles 0 and 1
  gload_lds16(kgp, &Kl[0][t * 8]);
  gload_lds16(vgp, &Vl[0][t * 8]);
  gload_lds16(kgp + (size_t)64 * HDIM, &Kl[1][t * 8]);
  gload_lds16(vgp + 64, &Vl[1][t * 8]);
  __syncthreads();

  // QK^T(0)
  f32x4 st[4] = {};
  __builtin_amdgcn_s_setprio(1);
#pragma unroll
  for (int nb = 0; nb < 4; ++nb)
#pragma unroll
    for (int kk = 0; kk < 2; ++kk) {
      const bfv8 kf = *(const bfv8*)&Kl[0][(nb * 16 + l15) * HDIM +
                                           (((kk * 4 + l4) ^ (l15 & 7)) * 8)];
      st[nb] = __builtin_amdgcn_mfma_f32_16x16x32_bf16(kf, qf[kk], st[nb], 0, 0, 0);
    }
  __builtin_amdgcn_s_setprio(0);

  for (int kt = 0; kt < nt; ++kt) {
    const int cur = kt % 3, nxt = (kt + 1) % 3;
    if (kt + 2 < nt) {
      const int nv0 = (kt + 2) * 64;
      const int pre = (kt + 2) % 3;
      gload_lds16(kgp + (size_t)nv0 * HDIM, &Kl[pre][t * 8]);
      gload_lds16(vgp + nv0, &Vl[pre][t * 8]);
    }
    const bool actC = (kt * 64 <= wqmax);
    const bool actN = (kt + 1 < nt) && ((kt + 1) * 64 <= wqmax);

    bfv8 vf[4][2];
    if (actC) {
      // V fragments (latency hides under softmax VALU)
#pragma unroll
      for (int nd = 0; nd < 4; ++nd)
#pragma unroll
        for (int kk = 0; kk < 2; ++kk)
          vf[nd][kk] = *(const bfv8*)&Vl[cur][(nd * 16 + l15) * HDIM +
                                              (((kk * 4 + l4) ^ (l15 & 7)) * 8)];

      if (kt >= 2 * qt) {   // diagonal: causal mask
        const int kv0 = kt * 64;
#pragma unroll
        for (int nb = 0; nb < 4; ++nb)
#pragma unroll
          for (int r = 0; r < 4; ++r) {
            const int kgi = kv0 + nb * 16 + l4 * 4 + r;
            if (kgi > qg) st[nb][r] = -1e30f;
          }
      }

      // row max
      float pmn[4];
#pragma unroll
      for (int nb = 0; nb < 4; ++nb)
        pmn[nb] = fmaxf(fmaxf(st[nb][0], st[nb][1]), fmaxf(st[nb][2], st[nb][3]));
      float pm = fmaxf(fmaxf(pmn[0], pmn[1]), fmaxf(pmn[2], pmn[3]));
      pm = fmaxf(pm, __shfl_xor(pm, 16));
      { float a, b; swap32(pm, a, b); pm = fmaxf(a, b); }

      // defer-rescale (T13)
      if (!__all(pm - mreg <= 8.0f)) {
        const float mn = fmaxf(mreg, pm);
        const float al = exp2_hw(mreg - mn);
        mreg = mn;
        float alr[4];
#pragma unroll
        for (int r = 0; r < 4; ++r) alr[r] = bpermf(bp[r], al);
#pragma unroll
        for (int nd = 0; nd < 4; ++nd)
#pragma unroll
          for (int r = 0; r < 4; ++r) oacc[nd][r] *= alr[r];
        lreg *= al;
      }

      // P = exp2(st - m), row sum
      float ps[4] = {};
#pragma unroll
      for (int nb = 0; nb < 4; ++nb)
#pragma unroll
        for (int r = 0; r < 4; ++r) {
          const float p = exp2_hw(st[nb][r] - mreg);
          st[nb][r] = p;
          ps[nb] += p;
        }
      float pss = (ps[0] + ps[1]) + (ps[2] + ps[3]);
      pss += __shfl_xor(pss, 16);
      { float a, b; swap32(pss, a, b); pss = a + b; }
      lreg += pss;

      // pack P -> per-wave LDS
      asm volatile("" ::: "memory");
#pragma unroll
      for (int nb = 0; nb < 4; ++nb) {
        uint2 u;
        u.x = cvtpk_bf16(st[nb][0], st[nb][1]);
        u.y = cvtpk_bf16(st[nb][2], st[nb][3]);
        *(uint2*)&Pl[w][l15 * 72 + nb * 16 + l4 * 4] = u;
      }
      asm volatile("" ::: "memory");
    }

    // QK^T(kt+1) — independent of softmax(kt); fills MFMA pipe, hides P-store
    f32x4 stn[4] = {};
    if (actN) {
      __builtin_amdgcn_s_setprio(1);
#pragma unroll
      for (int nb = 0; nb < 4; ++nb)
#pragma unroll
        for (int kk = 0; kk < 2; ++kk) {
          const bfv8 kf = *(const bfv8*)&Kl[nxt][(nb * 16 + l15) * HDIM +
                                                 (((kk * 4 + l4) ^ (l15 & 7)) * 8)];
          stn[nb] = __builtin_amdgcn_mfma_f32_16x16x32_bf16(kf, qf[kk], stn[nb], 0, 0, 0);
        }
      __builtin_amdgcn_s_setprio(0);
    }

    if (actC) {
      // O += P V
      __builtin_amdgcn_s_setprio(1);
#pragma unroll
      for (int kk = 0; kk < 2; ++kk) {
        const bfv8 pf = *(const bfv8*)&Pl[w][l15 * 72 + kk * 32 + l4 * 8];
#pragma unroll
        for (int nd = 0; nd < 4; ++nd)
          oacc[nd] = __builtin_amdgcn_mfma_f32_16x16x32_bf16(pf, vf[nd][kk], oacc[nd], 0, 0, 0);
      }
      __builtin_amdgcn_s_setprio(0);
    }

#pragma unroll
    for (int nb = 0; nb < 4; ++nb) st[nb] = stn[nb];
    __syncthreads();
  }

  const int b = bh >> 3, h = bh & 7;
  const float linv = 1.0f / lreg;
  float lr[4];
#pragma unroll
  for (int r = 0; r < 4; ++r) lr[r] = bpermf(bp[r], linv);
#pragma unroll
  for (int nd = 0; nd < 4; ++nd)
#pragma unroll
    for (int r = 0; r < 4; ++r) {
      const int q = q0 + w * 16 + l4 * 4 + r;
      O[((size_t)(b * SEQ + q)) * D_MODEL + h * HDIM + nd * 16 + l15] =
          (bf16)(oacc[nd][r] * lr[r]);
    }
}

// ---------------- launch ----------------
extern "C" void kernel_launch(void* const* d_in, const int* in_sizes, int n_in,
                              void* d_out, int out_size, void* d_ws, size_t ws_size,
                              hipStream_t stream) {
  const float* x    = (const float*)d_in[0];
  const float* Wqkv = (const float*)d_in[1];
  const float* bqkv = (const float*)d_in[2];
  const float* Wo   = (const float*)d_in[3];
  const float* bo   = (const float*)d_in[4];
  float* out = (float*)d_out;

  bf16* xb  = (bf16*)d_ws;
  bf16* wqt = xb + (size_t)NTOK * D_MODEL;
  bf16* wot = wqt + (size_t)1536 * 512;
  bf16* Qb  = wot + (size_t)512 * 512;
  bf16* Kb  = Qb + (size_t)16 * SEQ * HDIM;
  bf16* Vb  = Kb + (size_t)16 * SEQ * HDIM;   // V transposed [bh][d][s]
  bf16* Ob  = Vb + (size_t)16 * SEQ * HDIM;

  k_cvt<<<(NTOK * D_MODEL / 4 + 255) / 256, 256, 0, stream>>>(x, xb, NTOK * D_MODEL);
  k_cvt_t<<<dim3(1536 / 64, 512 / 64), 256, 0, stream>>>(Wqkv, wqt, 512, 1536);
  k_cvt_t<<<dim3(512 / 64, 512 / 64), 256, 0, stream>>>(Wo, wot, 512, 512);

  k_gemm_bt<1><<<dim3(1536 / 128, NTOK / 128), 256, 0, stream>>>(
      xb, wqt, bqkv, nullptr, Qb, Kb, Vb);

  k_attn<<<dim3(512), 512, 0, stream>>>(Qb, Kb, Vb, Ob);

  k_gemm_bt<0><<<dim3(512 / 128, NTOK / 128), 256, 0, stream>>>(
      Ob, wot, bo, out, nullptr, nullptr, nullptr);
}

// Round 6
// 137.174 us; speedup vs baseline: 1.0239x; 1.0239x over previous
//
#include <hip/hip_runtime.h>
#include <hip/hip_bf16.h>
#include <cstdint>

#define D_MODEL 512
#define NHEADS 8
#define HDIM 64
#define SEQ 4096
#define BATCH 2
#define NTOK (BATCH*SEQ)

typedef __bf16 bf16;
typedef __bf16 bfv8 __attribute__((ext_vector_type(8)));
typedef __bf16 bfv4 __attribute__((ext_vector_type(4)));
typedef float f32x4 __attribute__((ext_vector_type(4)));
typedef float f32x16 __attribute__((ext_vector_type(16)));
typedef unsigned u32x2 __attribute__((ext_vector_type(2)));

__device__ __forceinline__ void gload_lds16(const void* g, void* l) {
  __builtin_amdgcn_global_load_lds(
      (const __attribute__((address_space(1))) void*)(uintptr_t)g,
      (__attribute__((address_space(3))) void*)(uintptr_t)l,
      16, 0, 0);
}
__device__ __forceinline__ float exp2_hw(float x) {
  float r; asm("v_exp_f32 %0, %1" : "=v"(r) : "v"(x)); return r;
}
__device__ __forceinline__ unsigned cvtpk_bf16(float lo, float hi) {
  unsigned r; asm("v_cvt_pk_bf16_f32 %0, %1, %2" : "=v"(r) : "v"(lo), "v"(hi)); return r;
}
__device__ __forceinline__ float bpermf(int addr, float v) {
  return __int_as_float(__builtin_amdgcn_ds_bpermute(addr, __float_as_int(v)));
}
// symmetric cross-half pair — only used with max/sum (order-robust)
__device__ __forceinline__ void swap32(float x, float& a, float& b) {
  u32x2 r = __builtin_amdgcn_permlane32_swap(__float_as_uint(x), __float_as_uint(x), false, false);
  a = __uint_as_float(r[0]); b = __uint_as_float(r[1]);
}

// ---------------- converters ----------------
__global__ void k_cvt(const float* __restrict__ in, bf16* __restrict__ out, int n) {
  int i = (blockIdx.x * blockDim.x + threadIdx.x) * 4;
  if (i < n) {
    const float4 v = *(const float4*)(in + i);
    bfv4 b;
    b[0] = (bf16)v.x; b[1] = (bf16)v.y; b[2] = (bf16)v.z; b[3] = (bf16)v.w;
    *(bfv4*)(out + i) = b;
  }
}

__global__ __launch_bounds__(256) void k_cvt_t(
    const float* __restrict__ w, bf16* __restrict__ wt, int K, int N) {
  __shared__ float tile[64][65];
  const int n0 = blockIdx.x * 64, k0 = blockIdx.y * 64;
  const int c = threadIdx.x & 63, r0 = threadIdx.x >> 6;
#pragma unroll
  for (int i = 0; i < 16; ++i) {
    const int r = r0 + i * 4;
    tile[r][c] = w[(size_t)(k0 + r) * N + n0 + c];
  }
  __syncthreads();
#pragma unroll
  for (int i = 0; i < 16; ++i) {
    const int r = r0 + i * 4;
    wt[(size_t)(n0 + r) * K + k0 + c] = (bf16)tile[c][r];
  }
}

// ---------------- GEMM C = A * Bt^T (+bias)  (BK=32) ----------------
template<int EPI>
__global__ __launch_bounds__(256) void k_gemm_bt(
    const bf16* __restrict__ A, const bf16* __restrict__ Bt,
    const float* __restrict__ bias,
    float* __restrict__ Cf,
    bf16* __restrict__ Qo, bf16* __restrict__ Ko, bf16* __restrict__ Vo)
{
  __shared__ bf16 As[128 * 32];
  __shared__ bf16 Bs[128 * 32];
  const int t = threadIdx.x;
  const int lane = t & 63;
  const int w = t >> 6;
  const int wm = w >> 1, wn = w & 1;
  const int l15 = lane & 15, l4 = lane >> 4;
  const int bm = blockIdx.y, bn = blockIdx.x;

  const int srow = t >> 2;
  const int scol = (t & 3) * 8;
  const bf16* gA = A + (size_t)(bm * 128 + srow) * D_MODEL + scol;
  const bf16* gB = Bt + (size_t)(bn * 128 + srow) * D_MODEL + scol;
  bf16* lA = &As[srow * 32 + scol];
  bf16* lB = &Bs[srow * 32 + scol];

  f32x4 acc[4][4] = {};

  for (int kt = 0; kt < D_MODEL / 32; ++kt) {
    const int k0 = kt * 32;
    gload_lds16(gA + k0, lA);
    gload_lds16(gA + (size_t)64 * D_MODEL + k0, lA + 64 * 32);
    gload_lds16(gB + k0, lB);
    gload_lds16(gB + (size_t)64 * D_MODEL + k0, lB + 64 * 32);
    __syncthreads();
    bfv8 af[4], bfr[4];
#pragma unroll
    for (int m = 0; m < 4; ++m)
      af[m] = *(const bfv8*)&As[(wm * 64 + m * 16 + l15) * 32 + l4 * 8];
#pragma unroll
    for (int n = 0; n < 4; ++n)
      bfr[n] = *(const bfv8*)&Bs[(wn * 64 + n * 16 + l15) * 32 + l4 * 8];
#pragma unroll
    for (int m = 0; m < 4; ++m)
#pragma unroll
      for (int n = 0; n < 4; ++n)
        acc[m][n] = __builtin_amdgcn_mfma_f32_16x16x32_bf16(af[m], bfr[n], acc[m][n], 0, 0, 0);
    __syncthreads();
  }

#pragma unroll
  for (int m = 0; m < 4; ++m) {
#pragma unroll
    for (int n = 0; n < 4; ++n) {
      const int col = bn * 128 + wn * 64 + n * 16 + l15;
      const float bv = bias[col];
#pragma unroll
      for (int r = 0; r < 4; ++r) {
        const int row = bm * 128 + wm * 64 + m * 16 + l4 * 4 + r;
        const float val = acc[m][n][r] + bv;
        if constexpr (EPI == 0) {
          Cf[(size_t)row * D_MODEL + col] = val;
        } else {
          const int which = col >> 9;
          const int rem = col & 511;
          const int h = rem >> 6, dd = rem & 63;
          const int b = row >> 12, s = row & 4095;
          const int bh = b * NHEADS + h;
          if (which == 0)
            Qo[(((size_t)bh) * SEQ + s) * HDIM + dd] = (bf16)(val * 0.18033688f); // 1/8*log2(e)
          else if (which == 1)
            Ko[(((size_t)bh) * SEQ + s) * HDIM + dd] = (bf16)val;
          else
            Vo[(((size_t)bh) * HDIM + dd) * SEQ + s] = (bf16)val;  // transposed
        }
      }
    }
  }
}

// ---------------- causal flash attention (32x32 MFMA, P fully in-register) ------
// 512 blocks zigzag; 4 waves x 32 q-rows (QBLK=128). K/V double-buffered in LDS
// (source-swizzled chunks). Lane pair (l, l^32) owns q-row = lane&31.
__global__ __launch_bounds__(256, 4) void k_attn(
    const bf16* __restrict__ Q, const bf16* __restrict__ Kg,
    const bf16* __restrict__ Vt, bf16* __restrict__ O)
{
  __shared__ __align__(16) bf16 Kl[2][4096];   // [kv 64][d 64], chunk-swizzled
  __shared__ __align__(16) bf16 Vl[2][4096];   // [d 64][kv 64], chunk-swizzled
  const int t = threadIdx.x;
  const int lane = t & 63, w = t >> 6;
  const int l31 = lane & 31, hh = lane >> 5;
  const int bx = blockIdx.x;
  const int bh = bx & 15;
  const int qt = (bx < 256) ? (31 - (bx >> 4)) : ((bx - 256) >> 4);  // zigzag pairs
  const size_t kqbase = (size_t)bh * SEQ * HDIM;
  const size_t vbase  = (size_t)bh * HDIM * SEQ;
  const int q0 = qt * 128;

  // ---- permlane32_swap convention probe ----
  // Want: plswap(P,Q) -> lo[l] = l<32 ? P[l] : Q[l-32]; hi[l] = l<32 ? P[l+32] : Q[l].
  // Probe x={1|2}, y={3|4} (lo|hi halves): lane0 of ret[0] in {1,2,3,4} identifies
  // {direction, order}: mode = value-1; bit1 = swapped operands, bit0 = swapped returns.
  bool flipD, flipO;
  {
    const unsigned x = hh ? 2u : 1u, y = hh ? 4u : 3u;
    u32x2 r = __builtin_amdgcn_permlane32_swap(x, y, false, false);
    const int mode = (int)__builtin_amdgcn_readfirstlane(r[0]) - 1;
    flipD = (mode & 2) != 0;
    flipO = (mode & 1) != 0;
  }
  auto plswap = [&](unsigned P, unsigned Q, unsigned& lo, unsigned& hi) {
    const unsigned a = flipD ? Q : P, b = flipD ? P : Q;
    const u32x2 r = __builtin_amdgcn_permlane32_swap(a, b, false, false);
    lo = flipO ? r[1] : r[0];
    hi = flipO ? r[0] : r[1];
  };

  // staging: 512 chunks of 16B per tensor; thread t handles chunks t, t+256.
  const int r0 = t >> 3,          c0 = ((t & 7) ^ (r0 & 7)) * 8;
  const int r1 = (t + 256) >> 3,  c1 = (((t + 256) & 7) ^ (r1 & 7)) * 8;
  const bf16* kgp0 = Kg + kqbase + (size_t)r0 * HDIM + c0;
  const bf16* kgp1 = Kg + kqbase + (size_t)r1 * HDIM + c1;
  const bf16* vgp0 = Vt + vbase + (size_t)r0 * SEQ + c0;
  const bf16* vgp1 = Vt + vbase + (size_t)r1 * SEQ + c1;

  // Q B-fragments: lane holds Q[q0+32w+l31][16s+8hh+j]
  bfv8 qreg[4];
  {
    const bf16* qp = Q + kqbase + (size_t)(q0 + w * 32 + l31) * HDIM + hh * 8;
#pragma unroll
    for (int s = 0; s < 4; ++s) qreg[s] = *(const bfv8*)(qp + s * 16);
  }
  const int qg = q0 + w * 32 + l31;        // this lane's q row
  const int wqmin = q0 + w * 32;
  const int wqmax = q0 + w * 32 + 31;

  f32x16 oacc[2] = {};
  float mreg = -1e30f;
  float lreg = 0.f;

  const int nt = 2 * qt + 2;

  // prologue: stage tile 0 -> buf 0
  gload_lds16(kgp0, &Kl[0][t * 8]);
  gload_lds16(kgp1, &Kl[0][(t + 256) * 8]);
  gload_lds16(vgp0, &Vl[0][t * 8]);
  gload_lds16(vgp1, &Vl[0][(t + 256) * 8]);
  __syncthreads();

  for (int kt = 0; kt < nt; ++kt) {
    const int buf = kt & 1;
    if (kt + 1 < nt) {
      const size_t ko = (size_t)(kt + 1) * 64 * HDIM;
      const int vo = (kt + 1) * 64;
      gload_lds16(kgp0 + ko, &Kl[buf ^ 1][t * 8]);
      gload_lds16(kgp1 + ko, &Kl[buf ^ 1][(t + 256) * 8]);
      gload_lds16(vgp0 + vo, &Vl[buf ^ 1][t * 8]);
      gload_lds16(vgp1 + vo, &Vl[buf ^ 1][(t + 256) * 8]);
    }
    const int kv0 = kt * 64;

    if (kv0 <= wqmax) {
      // ---- S^T = K Q^T : st[blk] rows kv(32), cols q(32) ----
      f32x16 st[2] = {};
      __builtin_amdgcn_s_setprio(1);
#pragma unroll
      for (int blk = 0; blk < 2; ++blk)
#pragma unroll
        for (int s = 0; s < 4; ++s) {
          const int row = 32 * blk + l31;
          const bfv8 kf = *(const bfv8*)&Kl[buf][row * 64 + (((2 * s + hh) ^ (row & 7)) * 8)];
          st[blk] = __builtin_amdgcn_mfma_f32_32x32x16_bf16(kf, qreg[s], st[blk], 0, 0, 0);
        }
      __builtin_amdgcn_s_setprio(0);

      // causal mask (only tiles crossing this wave's diagonal)
      if (kv0 + 63 > wqmin) {
#pragma unroll
        for (int blk = 0; blk < 2; ++blk)
#pragma unroll
          for (int e = 0; e < 16; ++e) {
            const int kvg = kv0 + 32 * blk + (e & 3) + 8 * (e >> 2) + 4 * hh;
            if (kvg > qg) st[blk][e] = -1e30f;
          }
      }

      // ---- row max: in-lane tree over 32 + cross-half swap ----
      float pm;
      {
        float m0 = fmaxf(fmaxf(st[0][0], st[0][1]), fmaxf(st[0][2], st[0][3]));
        float m1 = fmaxf(fmaxf(st[0][4], st[0][5]), fmaxf(st[0][6], st[0][7]));
        float m2 = fmaxf(fmaxf(st[0][8], st[0][9]), fmaxf(st[0][10], st[0][11]));
        float m3 = fmaxf(fmaxf(st[0][12], st[0][13]), fmaxf(st[0][14], st[0][15]));
        float m4 = fmaxf(fmaxf(st[1][0], st[1][1]), fmaxf(st[1][2], st[1][3]));
        float m5 = fmaxf(fmaxf(st[1][4], st[1][5]), fmaxf(st[1][6], st[1][7]));
        float m6 = fmaxf(fmaxf(st[1][8], st[1][9]), fmaxf(st[1][10], st[1][11]));
        float m7 = fmaxf(fmaxf(st[1][12], st[1][13]), fmaxf(st[1][14], st[1][15]));
        pm = fmaxf(fmaxf(fmaxf(m0, m1), fmaxf(m2, m3)), fmaxf(fmaxf(m4, m5), fmaxf(m6, m7)));
        float a, b; swap32(pm, a, b); pm = fmaxf(a, b);
      }

      // ---- defer-rescale (T13) ----
      if (!__all(pm - mreg <= 8.0f)) {
        const float mn = fmaxf(mreg, pm);
        const float al = exp2_hw(mreg - mn);
        mreg = mn;
#pragma unroll
        for (int e = 0; e < 16; ++e) {
          const float ae = bpermf(4 * ((e & 3) + 8 * (e >> 2) + 4 * hh), al);
          oacc[0][e] *= ae;
          oacc[1][e] *= ae;
        }
        lreg *= al;
      }

      // ---- P = exp2(st - m); row sum ----
      float ps = 0.f;
#pragma unroll
      for (int blk = 0; blk < 2; ++blk)
#pragma unroll
        for (int e = 0; e < 16; ++e) {
          const float p = exp2_hw(st[blk][e] - mreg);
          st[blk][e] = p;
          ps += p;
        }
      {
        float a, b; swap32(ps, a, b); ps = a + b;
      }
      lreg += ps;

      // ---- PV: assemble P A-frags in-register (cvt_pk + permlane32_swap) ----
      // For K-step g=2blk+sp (kv-local rows 16sp..16sp+15 within blk), identity
      // k-slot order: hh=0 lane needs rows (0,1),(2,3),(4,5),(6,7); hh=1 rows 8..15.
      // Own regs: P0a=(4hh,4hh+1), P0b=(4hh+2,4hh+3), P1a=(8+4hh,9+4hh), P1b=(10+4hh,11+4hh).
      // plswap(P0a,P1a): lo = hh=0: own(0,1) / hh=1: partner(8,9)   -> u[0]
      //                  hi = hh=0: partner(4,5) / hh=1: own(12,13) -> u[2]
      __builtin_amdgcn_s_setprio(1);
#pragma unroll
      for (int blk = 0; blk < 2; ++blk)
#pragma unroll
        for (int sp = 0; sp < 2; ++sp) {
          const unsigned P0a = cvtpk_bf16(st[blk][8 * sp + 0], st[blk][8 * sp + 1]);
          const unsigned P0b = cvtpk_bf16(st[blk][8 * sp + 2], st[blk][8 * sp + 3]);
          const unsigned P1a = cvtpk_bf16(st[blk][8 * sp + 4], st[blk][8 * sp + 5]);
          const unsigned P1b = cvtpk_bf16(st[blk][8 * sp + 6], st[blk][8 * sp + 7]);
          union { unsigned u[4]; bfv8 v; } pu;
          plswap(P0a, P1a, pu.u[0], pu.u[2]);
          plswap(P0b, P1b, pu.u[1], pu.u[3]);
          const int g = 2 * blk + sp;
#pragma unroll
          for (int nd = 0; nd < 2; ++nd) {
            const int drow = 32 * nd + l31;
            const bfv8 vf = *(const bfv8*)&Vl[buf][drow * 64 + (((2 * g + hh) ^ (drow & 7)) * 8)];
            oacc[nd] = __builtin_amdgcn_mfma_f32_32x32x16_bf16(pu.v, vf, oacc[nd], 0, 0, 0);
          }
        }
      __builtin_amdgcn_s_setprio(0);
    }
    __syncthreads();
  }

  // ---- epilogue ----
  const int b = bh >> 3, hd = bh & 7;
  const float linv = 1.0f / lreg;
#pragma unroll
  for (int e = 0; e < 16; ++e) {
    const int qloc = (e & 3) + 8 * (e >> 2) + 4 * hh;
    const float le = bpermf(4 * qloc, linv);
    const int q = q0 + w * 32 + qloc;
    const size_t rowb = ((size_t)(b * SEQ + q)) * D_MODEL + hd * HDIM;
    O[rowb + l31]      = (bf16)(oacc[0][e] * le);
    O[rowb + 32 + l31] = (bf16)(oacc[1][e] * le);
  }
}

// ---------------- launch ----------------
extern "C" void kernel_launch(void* const* d_in, const int* in_sizes, int n_in,
                              void* d_out, int out_size, void* d_ws, size_t ws_size,
                              hipStream_t stream) {
  const float* x    = (const float*)d_in[0];
  const float* Wqkv = (const float*)d_in[1];
  const float* bqkv = (const float*)d_in[2];
  const float* Wo   = (const float*)d_in[3];
  const float* bo   = (const float*)d_in[4];
  float* out = (float*)d_out;

  bf16* xb  = (bf16*)d_ws;
  bf16* wqt = xb + (size_t)NTOK * D_MODEL;
  bf16* wot = wqt + (size_t)1536 * 512;
  bf16* Qb  = wot + (size_t)512 * 512;
  bf16* Kb  = Qb + (size_t)16 * SEQ * HDIM;
  bf16* Vb  = Kb + (size_t)16 * SEQ * HDIM;   // V transposed [bh][d][s]
  bf16* Ob  = Vb + (size_t)16 * SEQ * HDIM;

  k_cvt<<<(NTOK * D_MODEL / 4 + 255) / 256, 256, 0, stream>>>(x, xb, NTOK * D_MODEL);
  k_cvt_t<<<dim3(1536 / 64, 512 / 64), 256, 0, stream>>>(Wqkv, wqt, 512, 1536);
  k_cvt_t<<<dim3(512 / 64, 512 / 64), 256, 0, stream>>>(Wo, wot, 512, 512);

  k_gemm_bt<1><<<dim3(1536 / 128, NTOK / 128), 256, 0, stream>>>(
      xb, wqt, bqkv, nullptr, Qb, Kb, Vb);

  k_attn<<<dim3(512), 256, 0, stream>>>(Qb, Kb, Vb, Ob);

  k_gemm_bt<0><<<dim3(512 / 128, NTOK / 128), 256, 0, stream>>>(
      Ob, wot, bo, out, nullptr, nullptr, nullptr);
}

// Round 7
// 119.194 us; speedup vs baseline: 1.1784x; 1.1508x over previous
//
#include <hip/hip_runtime.h>
#include <hip/hip_bf16.h>
#include <cstdint>

#define D_MODEL 512
#define NHEADS 8
#define HDIM 64
#define SEQ 4096
#define BATCH 2
#define NTOK (BATCH*SEQ)

typedef __bf16 bf16;
typedef __bf16 bfv8 __attribute__((ext_vector_type(8)));
typedef __bf16 bfv4 __attribute__((ext_vector_type(4)));
typedef float f32x4 __attribute__((ext_vector_type(4)));
typedef float f32x16 __attribute__((ext_vector_type(16)));
typedef unsigned u32x2 __attribute__((ext_vector_type(2)));

__device__ __forceinline__ void gload_lds16(const void* g, void* l) {
  __builtin_amdgcn_global_load_lds(
      (const __attribute__((address_space(1))) void*)(uintptr_t)g,
      (__attribute__((address_space(3))) void*)(uintptr_t)l,
      16, 0, 0);
}
__device__ __forceinline__ float exp2_hw(float x) {
  float r; asm("v_exp_f32 %0, %1" : "=v"(r) : "v"(x)); return r;
}
__device__ __forceinline__ unsigned cvtpk_bf16(float lo, float hi) {
  unsigned r; asm("v_cvt_pk_bf16_f32 %0, %1, %2" : "=v"(r) : "v"(lo), "v"(hi)); return r;
}
__device__ __forceinline__ float bpermf(int addr, float v) {
  return __int_as_float(__builtin_amdgcn_ds_bpermute(addr, __float_as_int(v)));
}
// symmetric cross-half pair — only used with max/sum (order-robust)
__device__ __forceinline__ void swap32(float x, float& a, float& b) {
  u32x2 r = __builtin_amdgcn_permlane32_swap(__float_as_uint(x), __float_as_uint(x), false, false);
  a = __uint_as_float(r[0]); b = __uint_as_float(r[1]);
}

// ---------------- converters ----------------
__global__ void k_cvt(const float* __restrict__ in, bf16* __restrict__ out, int n) {
  int i = (blockIdx.x * blockDim.x + threadIdx.x) * 4;
  if (i < n) {
    const float4 v = *(const float4*)(in + i);
    bfv4 b;
    b[0] = (bf16)v.x; b[1] = (bf16)v.y; b[2] = (bf16)v.z; b[3] = (bf16)v.w;
    *(bfv4*)(out + i) = b;
  }
}

__global__ __launch_bounds__(256) void k_cvt_t(
    const float* __restrict__ w, bf16* __restrict__ wt, int K, int N) {
  __shared__ float tile[64][65];
  const int n0 = blockIdx.x * 64, k0 = blockIdx.y * 64;
  const int c = threadIdx.x & 63, r0 = threadIdx.x >> 6;
#pragma unroll
  for (int i = 0; i < 16; ++i) {
    const int r = r0 + i * 4;
    tile[r][c] = w[(size_t)(k0 + r) * N + n0 + c];
  }
  __syncthreads();
#pragma unroll
  for (int i = 0; i < 16; ++i) {
    const int r = r0 + i * 4;
    wt[(size_t)(n0 + r) * K + k0 + c] = (bf16)tile[c][r];
  }
}

// ---------------- GEMM C = A * Bt^T (+bias)  (BK=32) ----------------
template<int EPI>
__global__ __launch_bounds__(256) void k_gemm_bt(
    const bf16* __restrict__ A, const bf16* __restrict__ Bt,
    const float* __restrict__ bias,
    float* __restrict__ Cf,
    bf16* __restrict__ Qo, bf16* __restrict__ Ko, bf16* __restrict__ Vo)
{
  __shared__ bf16 As[128 * 32];
  __shared__ bf16 Bs[128 * 32];
  const int t = threadIdx.x;
  const int lane = t & 63;
  const int w = t >> 6;
  const int wm = w >> 1, wn = w & 1;
  const int l15 = lane & 15, l4 = lane >> 4;
  const int bm = blockIdx.y, bn = blockIdx.x;

  const int srow = t >> 2;
  const int scol = (t & 3) * 8;
  const bf16* gA = A + (size_t)(bm * 128 + srow) * D_MODEL + scol;
  const bf16* gB = Bt + (size_t)(bn * 128 + srow) * D_MODEL + scol;
  bf16* lA = &As[srow * 32 + scol];
  bf16* lB = &Bs[srow * 32 + scol];

  f32x4 acc[4][4] = {};

  for (int kt = 0; kt < D_MODEL / 32; ++kt) {
    const int k0 = kt * 32;
    gload_lds16(gA + k0, lA);
    gload_lds16(gA + (size_t)64 * D_MODEL + k0, lA + 64 * 32);
    gload_lds16(gB + k0, lB);
    gload_lds16(gB + (size_t)64 * D_MODEL + k0, lB + 64 * 32);
    __syncthreads();
    bfv8 af[4], bfr[4];
#pragma unroll
    for (int m = 0; m < 4; ++m)
      af[m] = *(const bfv8*)&As[(wm * 64 + m * 16 + l15) * 32 + l4 * 8];
#pragma unroll
    for (int n = 0; n < 4; ++n)
      bfr[n] = *(const bfv8*)&Bs[(wn * 64 + n * 16 + l15) * 32 + l4 * 8];
#pragma unroll
    for (int m = 0; m < 4; ++m)
#pragma unroll
      for (int n = 0; n < 4; ++n)
        acc[m][n] = __builtin_amdgcn_mfma_f32_16x16x32_bf16(af[m], bfr[n], acc[m][n], 0, 0, 0);
    __syncthreads();
  }

#pragma unroll
  for (int m = 0; m < 4; ++m) {
#pragma unroll
    for (int n = 0; n < 4; ++n) {
      const int col = bn * 128 + wn * 64 + n * 16 + l15;
      const float bv = bias[col];
#pragma unroll
      for (int r = 0; r < 4; ++r) {
        const int row = bm * 128 + wm * 64 + m * 16 + l4 * 4 + r;
        const float val = acc[m][n][r] + bv;
        if constexpr (EPI == 0) {
          Cf[(size_t)row * D_MODEL + col] = val;
        } else {
          const int which = col >> 9;
          const int rem = col & 511;
          const int h = rem >> 6, dd = rem & 63;
          const int b = row >> 12, s = row & 4095;
          const int bh = b * NHEADS + h;
          if (which == 0)
            Qo[(((size_t)bh) * SEQ + s) * HDIM + dd] = (bf16)(val * 0.18033688f); // 1/8*log2(e)
          else if (which == 1)
            Ko[(((size_t)bh) * SEQ + s) * HDIM + dd] = (bf16)val;
          else
            Vo[(((size_t)bh) * HDIM + dd) * SEQ + s] = (bf16)val;  // transposed
        }
      }
    }
  }
}

// ---------------- causal flash attention ----------------
// 512 blocks zigzag; 512 threads = 8 waves: groups A(w0-3)/B(w4-7) process
// even/odd kv tiles of the same 128-row q-tile (kv-split), private (m,l,O),
// merged through LDS at the end. 32x32 MFMA, P fully in-register.
__global__ __launch_bounds__(512, 4) void k_attn(
    const bf16* __restrict__ Q, const bf16* __restrict__ Kg,
    const bf16* __restrict__ Vt, bf16* __restrict__ O)
{
  __shared__ __align__(16) bf16 Kl[4][4096];   // 2 phases x 2 tiles, [kv 64][d 64] swizzled
  __shared__ __align__(16) bf16 Vl[4][4096];   // 2 phases x 2 tiles, [d 64][kv 64] swizzled
  const int t = threadIdx.x;
  const int lane = t & 63, w = t >> 6;
  const int wq = w & 3, grp = w >> 2;          // wave pair (wq, grp)
  const int l31 = lane & 31, hh = lane >> 5;
  const int bx = blockIdx.x;
  const int bh = bx & 15;
  const int qt = (bx < 256) ? (31 - (bx >> 4)) : ((bx - 256) >> 4);  // zigzag pairs
  const size_t kqbase = (size_t)bh * SEQ * HDIM;
  const size_t vbase  = (size_t)bh * HDIM * SEQ;
  const int q0 = qt * 128;

  // ---- permlane32_swap convention probe (same as verified R6) ----
  bool flipD, flipO;
  {
    const unsigned x = hh ? 2u : 1u, y = hh ? 4u : 3u;
    u32x2 r = __builtin_amdgcn_permlane32_swap(x, y, false, false);
    const int mode = (int)__builtin_amdgcn_readfirstlane(r[0]) - 1;
    flipD = (mode & 2) != 0;
    flipO = (mode & 1) != 0;
  }
  auto plswap = [&](unsigned P, unsigned Q_, unsigned& lo, unsigned& hi) {
    const unsigned a = flipD ? Q_ : P, b = flipD ? P : Q_;
    const u32x2 r = __builtin_amdgcn_permlane32_swap(a, b, false, false);
    lo = flipO ? r[1] : r[0];
    hi = flipO ? r[0] : r[1];
  };

  // ---- staging: one PAIR of kv tiles (2 x 64kv) per phase; 4 chunks/thread ----
  // K chunk ch (0..1023): dest (phase base)+ch*16B; tile=ch>>9, c=ch&511,
  // r=c>>3, col=((c&7)^(r&7))*8; src row = pair*128 + tile*64 + r.
  const int chA = t, chB = t + 512;
  const int tA = chA >> 9, cA = chA & 511, rA = cA >> 3, colA = ((cA & 7) ^ (rA & 7)) * 8;
  const int tB = chB >> 9, cB = chB & 511, rB = cB >> 3, colB = ((cB & 7) ^ (rB & 7)) * 8;
  const bf16* kpA = Kg + kqbase + (size_t)(tA * 64 + rA) * HDIM + colA;
  const bf16* kpB = Kg + kqbase + (size_t)(tB * 64 + rB) * HDIM + colB;
  const bf16* vpA = Vt + vbase + (size_t)rA * SEQ + tA * 64 + colA;
  const bf16* vpB = Vt + vbase + (size_t)rB * SEQ + tB * 64 + colB;

  // Q B-fragments: lane holds Q[q0+32*wq+l31][16s+8hh+j]
  bfv8 qreg[4];
  {
    const bf16* qp = Q + kqbase + (size_t)(q0 + wq * 32 + l31) * HDIM + hh * 8;
#pragma unroll
    for (int s = 0; s < 4; ++s) qreg[s] = *(const bfv8*)(qp + s * 16);
  }
  const int qg = q0 + wq * 32 + l31;
  const int wqmin = q0 + wq * 32;
  const int wqmax = q0 + wq * 32 + 31;

  f32x16 oacc[2] = {};
  float mreg = -1e30f;
  float lreg = 0.f;

  const int np = qt + 1;   // kv tile pairs

  // prologue: stage pair 0 -> phase 0
  gload_lds16(kpA, &Kl[0][0] + chA * 8);
  gload_lds16(kpB, &Kl[0][0] + chB * 8);
  gload_lds16(vpA, &Vl[0][0] + chA * 8);
  gload_lds16(vpB, &Vl[0][0] + chB * 8);
  kpA += 8192; kpB += 8192; vpA += 128; vpB += 128;
  __syncthreads();

  for (int p = 0; p < np; ++p) {
    const int ph = p & 1;
    if (p + 1 < np) {
      bf16* kd = &Kl[0][0] + (ph ^ 1) * 8192;
      bf16* vd = &Vl[0][0] + (ph ^ 1) * 8192;
      gload_lds16(kpA, kd + chA * 8);
      gload_lds16(kpB, kd + chB * 8);
      gload_lds16(vpA, vd + chA * 8);
      gload_lds16(vpB, vd + chB * 8);
      kpA += 8192; kpB += 8192; vpA += 128; vpB += 128;
    }
    const int kt = 2 * p + grp;
    const int kv0 = kt * 64;

    if (kv0 <= wqmax) {
      const bf16* kbase = &Kl[0][0] + (ph * 2 + grp) * 4096;
      const bf16* vbase_l = &Vl[0][0] + (ph * 2 + grp) * 4096;

      // ---- S^T = K Q^T ----
      f32x16 st[2] = {};
      __builtin_amdgcn_s_setprio(1);
#pragma unroll
      for (int blk = 0; blk < 2; ++blk)
#pragma unroll
        for (int s = 0; s < 4; ++s) {
          const int row = 32 * blk + l31;
          const bfv8 kf = *(const bfv8*)&kbase[row * 64 + (((2 * s + hh) ^ (row & 7)) * 8)];
          st[blk] = __builtin_amdgcn_mfma_f32_32x32x16_bf16(kf, qreg[s], st[blk], 0, 0, 0);
        }
      __builtin_amdgcn_s_setprio(0);

      // causal mask (tiles crossing this wave's diagonal)
      if (kv0 + 63 > wqmin) {
#pragma unroll
        for (int blk = 0; blk < 2; ++blk)
#pragma unroll
          for (int e = 0; e < 16; ++e) {
            const int kvg = kv0 + 32 * blk + (e & 3) + 8 * (e >> 2) + 4 * hh;
            if (kvg > qg) st[blk][e] = -1e30f;
          }
      }

      // ---- row max ----
      float pm;
      {
        float m0 = fmaxf(fmaxf(st[0][0], st[0][1]), fmaxf(st[0][2], st[0][3]));
        float m1 = fmaxf(fmaxf(st[0][4], st[0][5]), fmaxf(st[0][6], st[0][7]));
        float m2 = fmaxf(fmaxf(st[0][8], st[0][9]), fmaxf(st[0][10], st[0][11]));
        float m3 = fmaxf(fmaxf(st[0][12], st[0][13]), fmaxf(st[0][14], st[0][15]));
        float m4 = fmaxf(fmaxf(st[1][0], st[1][1]), fmaxf(st[1][2], st[1][3]));
        float m5 = fmaxf(fmaxf(st[1][4], st[1][5]), fmaxf(st[1][6], st[1][7]));
        float m6 = fmaxf(fmaxf(st[1][8], st[1][9]), fmaxf(st[1][10], st[1][11]));
        float m7 = fmaxf(fmaxf(st[1][12], st[1][13]), fmaxf(st[1][14], st[1][15]));
        pm = fmaxf(fmaxf(fmaxf(m0, m1), fmaxf(m2, m3)), fmaxf(fmaxf(m4, m5), fmaxf(m6, m7)));
        float a, b; swap32(pm, a, b); pm = fmaxf(a, b);
      }

      // ---- defer-rescale (T13) ----
      if (!__all(pm - mreg <= 8.0f)) {
        const float mn = fmaxf(mreg, pm);
        const float al = exp2_hw(mreg - mn);
        mreg = mn;
#pragma unroll
        for (int e = 0; e < 16; ++e) {
          const float ae = bpermf(4 * ((e & 3) + 8 * (e >> 2) + 4 * hh), al);
          oacc[0][e] *= ae;
          oacc[1][e] *= ae;
        }
        lreg *= al;
      }

      // ---- P = exp2(st - m); row sum ----
      float ps = 0.f;
#pragma unroll
      for (int blk = 0; blk < 2; ++blk)
#pragma unroll
        for (int e = 0; e < 16; ++e) {
          const float p_ = exp2_hw(st[blk][e] - mreg);
          st[blk][e] = p_;
          ps += p_;
        }
      {
        float a, b; swap32(ps, a, b); ps = a + b;
      }
      lreg += ps;

      // ---- PV: P A-frags in-register (verified R6 wiring) ----
      __builtin_amdgcn_s_setprio(1);
#pragma unroll
      for (int blk = 0; blk < 2; ++blk)
#pragma unroll
        for (int sp = 0; sp < 2; ++sp) {
          const unsigned P0a = cvtpk_bf16(st[blk][8 * sp + 0], st[blk][8 * sp + 1]);
          const unsigned P0b = cvtpk_bf16(st[blk][8 * sp + 2], st[blk][8 * sp + 3]);
          const unsigned P1a = cvtpk_bf16(st[blk][8 * sp + 4], st[blk][8 * sp + 5]);
          const unsigned P1b = cvtpk_bf16(st[blk][8 * sp + 6], st[blk][8 * sp + 7]);
          union { unsigned u[4]; bfv8 v; } pu;
          plswap(P0a, P1a, pu.u[0], pu.u[2]);
          plswap(P0b, P1b, pu.u[1], pu.u[3]);
          const int ks = 2 * blk + sp;
#pragma unroll
          for (int nd = 0; nd < 2; ++nd) {
            const int drow = 32 * nd + l31;
            const bfv8 vf = *(const bfv8*)&vbase_l[drow * 64 + (((2 * ks + hh) ^ (drow & 7)) * 8)];
            oacc[nd] = __builtin_amdgcn_mfma_f32_32x32x16_bf16(pu.v, vf, oacc[nd], 0, 0, 0);
          }
        }
      __builtin_amdgcn_s_setprio(0);
    }
    __syncthreads();
  }

  // ---- merge group B into group A via LDS ----
  float* ox = (float*)&Kl[0][0];          // 32 KB: [wq][e2 32][lane 64]
  float* mx = (float*)&Vl[0][0];          // m[256], l[256]
  if (grp == 1) {
#pragma unroll
    for (int nd = 0; nd < 2; ++nd)
#pragma unroll
      for (int e = 0; e < 16; ++e)
        ox[wq * 2048 + (nd * 16 + e) * 64 + lane] = oacc[nd][e];
    mx[wq * 64 + lane] = mreg;
    mx[256 + wq * 64 + lane] = lreg;
  }
  __syncthreads();

  if (grp == 0) {
    const float mB = mx[wq * 64 + lane];
    const float lB = mx[256 + wq * 64 + lane];
    const float M = fmaxf(mreg, mB);
    const float aA = exp2_hw(mreg - M);
    const float aB = exp2_hw(mB - M);
    const float lM = lreg * aA + lB * aB;
    const float linv = 1.0f / lM;

    const int b = bh >> 3, hd = bh & 7;
#pragma unroll
    for (int e = 0; e < 16; ++e) {
      const int qloc = (e & 3) + 8 * (e >> 2) + 4 * hh;
      const float fA = bpermf(4 * qloc, aA);
      const float fB = bpermf(4 * qloc, aB);
      const float le = bpermf(4 * qloc, linv);
      const float o0 = (oacc[0][e] * fA + ox[wq * 2048 + e * 64 + lane] * fB) * le;
      const float o1 = (oacc[1][e] * fA + ox[wq * 2048 + (16 + e) * 64 + lane] * fB) * le;
      const int q = q0 + wq * 32 + qloc;
      const size_t rowb = ((size_t)(b * SEQ + q)) * D_MODEL + hd * HDIM;
      O[rowb + l31]      = (bf16)o0;
      O[rowb + 32 + l31] = (bf16)o1;
    }
  }
}

// ---------------- launch ----------------
extern "C" void kernel_launch(void* const* d_in, const int* in_sizes, int n_in,
                              void* d_out, int out_size, void* d_ws, size_t ws_size,
                              hipStream_t stream) {
  const float* x    = (const float*)d_in[0];
  const float* Wqkv = (const float*)d_in[1];
  const float* bqkv = (const float*)d_in[2];
  const float* Wo   = (const float*)d_in[3];
  const float* bo   = (const float*)d_in[4];
  float* out = (float*)d_out;

  bf16* xb  = (bf16*)d_ws;
  bf16* wqt = xb + (size_t)NTOK * D_MODEL;
  bf16* wot = wqt + (size_t)1536 * 512;
  bf16* Qb  = wot + (size_t)512 * 512;
  bf16* Kb  = Qb + (size_t)16 * SEQ * HDIM;
  bf16* Vb  = Kb + (size_t)16 * SEQ * HDIM;   // V transposed [bh][d][s]
  bf16* Ob  = Vb + (size_t)16 * SEQ * HDIM;

  k_cvt<<<(NTOK * D_MODEL / 4 + 255) / 256, 256, 0, stream>>>(x, xb, NTOK * D_MODEL);
  k_cvt_t<<<dim3(1536 / 64, 512 / 64), 256, 0, stream>>>(Wqkv, wqt, 512, 1536);
  k_cvt_t<<<dim3(512 / 64, 512 / 64), 256, 0, stream>>>(Wo, wot, 512, 512);

  k_gemm_bt<1><<<dim3(1536 / 128, NTOK / 128), 256, 0, stream>>>(
      xb, wqt, bqkv, nullptr, Qb, Kb, Vb);

  k_attn<<<dim3(512), 512, 0, stream>>>(Qb, Kb, Vb, Ob);

  k_gemm_bt<0><<<dim3(512 / 128, NTOK / 128), 256, 0, stream>>>(
      Ob, wot, bo, out, nullptr, nullptr, nullptr);
}